// Round 11
// baseline (184.624 us; speedup 1.0000x reference)
//
#include <hip/hip_runtime.h>
#include <hip/hip_bf16.h>
#include <cstdint>
#include <cstddef>

typedef __attribute__((ext_vector_type(4))) float f32x4;
typedef __attribute__((ext_vector_type(8))) short bf16x8;

#define DEVI static __device__ __forceinline__

DEVI unsigned short f2bf(float f) {
  union { float f; unsigned int u; } v; v.f = f;
  unsigned int u = v.u;
  unsigned int r = (u + 0x7fffu + ((u >> 16) & 1u)) >> 16;
  return (unsigned short)r;
}

// packed fp32 pair -> bf16x2 in one VALU op (RNE)
DEVI unsigned int cvt_pk(float lo, float hi) {
  unsigned int r;
  asm("v_cvt_pk_bf16_f32 %0, %1, %2" : "=v"(r) : "v"(lo), "v"(hi));
  return r;
}

DEVI f32x4 mfma16(bf16x8 a, bf16x8 b, f32x4 c) {
  return __builtin_amdgcn_mfma_f32_16x16x32_bf16(a, b, c, 0, 0, 0);
}

// global -> LDS direct staging, 16B per lane (wave-uniform LDS base).
#define GLDS(gp, lp) __builtin_amdgcn_global_load_lds(                         \
    (const __attribute__((address_space(1))) void*)(const void*)(gp),          \
    (__attribute__((address_space(3))) void*)(void*)(lp), 16, 0, 0)

#define SBAR() asm volatile("s_barrier" ::: "memory")
#define WV(n) asm volatile("s_waitcnt vmcnt(" #n ")" ::: "memory")
#define FORCE4(x) asm volatile("" : "+v"(x))

// ---------------------------------------------------------------- convert ---
__global__ void convert_kernel(const float* __restrict__ hidden,
                               const float* __restrict__ qkv_w,
                               const float* __restrict__ o_w,
                               const float* __restrict__ scaling,
                               unsigned short* __restrict__ hbf,
                               unsigned short* __restrict__ wbf,
                               unsigned short* __restrict__ obf,
                               float* __restrict__ qscale) {
  int tid = blockIdx.x * blockDim.x + threadIdx.x;
  int nt = gridDim.x * blockDim.x;
  if (tid < 64) {
    float x = scaling[tid];
    float sp = (x > 20.f) ? x : log1pf(__expf(x));
    // (1.442695041/8)*softplus, times log2e so softmax can use exp2 directly.
    qscale[tid] = 0.1803368801243369f * 1.4426950408889634f * sp;
  }
  for (int i = tid; i < 1048576; i += nt) {
    float4 v = ((const float4*)hidden)[i];
    ushort4 o = { f2bf(v.x), f2bf(v.y), f2bf(v.z), f2bf(v.w) };
    ((ushort4*)hbf)[i] = o;
  }
  for (int i = tid; i < 393216; i += nt) {
    float4 v = ((const float4*)qkv_w)[i];
    ushort4 o = { f2bf(v.x), f2bf(v.y), f2bf(v.z), f2bf(v.w) };
    ((ushort4*)wbf)[i] = o;
  }
  for (int i = tid; i < 262144; i += nt) {
    float4 v = ((const float4*)o_w)[i];
    ushort4 o = { f2bf(v.x), f2bf(v.y), f2bf(v.z), f2bf(v.w) };
    ((ushort4*)obf)[i] = o;
  }
}

// ------------------------------------------------------ GEMM 1 (qkv proj) ---
// 64x192 tiles -> grid (8,64) = 512 UNIFORM blocks = exactly 2 blocks/CU
// (r9). 4 waves: wave w owns all 64 rows x cols [w*48, w*48+48).
__global__ __launch_bounds__(256, 2) void gemm_kernel(
    const unsigned short* __restrict__ A,
    const unsigned short* __restrict__ Bw,
    const float* __restrict__ bias,
    const float* __restrict__ qscale,
    unsigned short* __restrict__ oq,
    unsigned short* __restrict__ okv,
    unsigned short* __restrict__ ovt) {
  __shared__ __align__(16) unsigned short sA[64 * 64];
  __shared__ __align__(16) unsigned short sB[192 * 64];
  const int t = threadIdx.x, lane = t & 63, w = t >> 6;
  const int l15 = lane & 15, lg = lane >> 4;
  const int m0 = blockIdx.y * 64, n0 = blockIdx.x * 192;

  f32x4 acc[4][3] = {};

  for (int kb = 0; kb < 1024; kb += 64) {
    __syncthreads();
#pragma unroll
    for (int i = 0; i < 2; i++) {
      int idx = i * 256 + w * 64 + lane;
      int row = idx >> 3;
      int cg = (idx & 7) ^ (row & 7);
      GLDS(A + (size_t)(m0 + row) * 1024 + kb + cg * 8, sA + (i * 256 + w * 64) * 8);
    }
#pragma unroll
    for (int i = 0; i < 6; i++) {
      int idx = i * 256 + w * 64 + lane;
      int row = idx >> 3;
      int cg = (idx & 7) ^ (row & 7);
      GLDS(Bw + (size_t)(n0 + row) * 1024 + kb + cg * 8, sB + (i * 256 + w * 64) * 8);
    }
    __syncthreads();
    bf16x8 af[4][2], bfr[3][2];
#pragma unroll
    for (int rt = 0; rt < 4; rt++) {
      int row = rt * 16 + l15;
#pragma unroll
      for (int kk = 0; kk < 2; kk++) {
        int c = (kk * 4 + lg) ^ (row & 7);
        af[rt][kk] = *(const bf16x8*)((const char*)sA + row * 128 + c * 16);
      }
    }
#pragma unroll
    for (int ct = 0; ct < 3; ct++) {
      int rowb = w * 48 + ct * 16 + l15;
#pragma unroll
      for (int kk = 0; kk < 2; kk++) {
        int c = (kk * 4 + lg) ^ (rowb & 7);
        bfr[ct][kk] = *(const bf16x8*)((const char*)sB + rowb * 128 + c * 16);
      }
    }
#pragma unroll
    for (int kk = 0; kk < 2; kk++)
#pragma unroll
      for (int rt = 0; rt < 4; rt++)
#pragma unroll
        for (int ct = 0; ct < 3; ct++)
          acc[rt][ct] = mfma16(af[rt][kk], bfr[ct][kk], acc[rt][ct]);
  }

#pragma unroll
  for (int rt = 0; rt < 4; rt++) {
#pragma unroll
    for (int ct = 0; ct < 3; ct++) {
      int n = n0 + w * 48 + ct * 16 + l15;
      float bv = bias[n];
#pragma unroll
      for (int jj = 0; jj < 4; jj++) {
        int m = m0 + rt * 16 + lg * 4 + jj;
        float v = acc[rt][ct][jj] + bv;
        int b = m >> 11, s = m & 2047;
        if (n < 1024) {  // q: scaled, [b][h][s][d]
          int h = n >> 6, d = n & 63;
          v *= qscale[d];
          oq[(((size_t)(b * 16 + h) * 2048 + s) << 6) + d] = f2bf(v);
        } else if (n < 1280) {  // k: [b][kv][s][d]
          int kv = (n - 1024) >> 6, d = n & 63;
          okv[(((size_t)(b * 4 + kv) * 2048 + s) << 6) + d] = f2bf(v);
        } else {  // v transposed: [b][kv][d][s]
          int kv = (n - 1280) >> 6, d = n & 63;
          ovt[(((size_t)((b * 4 + kv) * 64 + d)) << 11) + s] = f2bf(v);
        }
      }
    }
  }
}

// ----------------------------------------------------- GEMM 2 (out proj) ----
// 64x128 tile -> grid (8,64) = 512 blocks = 2 blocks/CU. Transposed epilogue
// (r8): stage 32x64 f32 sub-tile in LDS (stride-68), store 4 full rows x
// 256B contiguous per instruction.
__global__ __launch_bounds__(256, 2) void gemm2_kernel(
    const unsigned short* __restrict__ A,    // [4096][1024] bf16
    const unsigned short* __restrict__ Bw,   // [1024][1024] bf16 (o_w)
    const float* __restrict__ bias,
    float* __restrict__ of) {
  __shared__ __align__(16) unsigned short sA[64 * 64];
  __shared__ __align__(16) unsigned short sB[128 * 64];
  __shared__ __align__(16) float sT[4][32 * 68];
  const int t = threadIdx.x, lane = t & 63, w = t >> 6;
  const int l15 = lane & 15, lg = lane >> 4;
  const int m0 = blockIdx.y * 64, n0 = blockIdx.x * 128;
  const int wr = w >> 1, wc = w & 1;  // 2x2 wave grid over 64x128

  f32x4 acc[2][4] = {};

  for (int kb = 0; kb < 1024; kb += 64) {
    __syncthreads();
#pragma unroll
    for (int i = 0; i < 2; i++) {
      int idx = i * 256 + w * 64 + lane;
      int row = idx >> 3;
      int cg = (idx & 7) ^ (row & 7);
      GLDS(A + (size_t)(m0 + row) * 1024 + kb + cg * 8, sA + (i * 256 + w * 64) * 8);
    }
#pragma unroll
    for (int i = 0; i < 4; i++) {
      int idx = i * 256 + w * 64 + lane;
      int row = idx >> 3;
      int cg = (idx & 7) ^ (row & 7);
      GLDS(Bw + (size_t)(n0 + row) * 1024 + kb + cg * 8, sB + (i * 256 + w * 64) * 8);
    }
    __syncthreads();
    bf16x8 af[2][2], bfr[4][2];
#pragma unroll
    for (int rt = 0; rt < 2; rt++) {
      int row = wr * 32 + rt * 16 + l15;
#pragma unroll
      for (int kk = 0; kk < 2; kk++) {
        int c = (kk * 4 + lg) ^ (row & 7);
        af[rt][kk] = *(const bf16x8*)((const char*)sA + row * 128 + c * 16);
      }
    }
#pragma unroll
    for (int ct = 0; ct < 4; ct++) {
      int rowb = wc * 64 + ct * 16 + l15;
#pragma unroll
      for (int kk = 0; kk < 2; kk++) {
        int c = (kk * 4 + lg) ^ (rowb & 7);
        bfr[ct][kk] = *(const bf16x8*)((const char*)sB + rowb * 128 + c * 16);
      }
    }
#pragma unroll
    for (int kk = 0; kk < 2; kk++)
#pragma unroll
      for (int rt = 0; rt < 2; rt++)
#pragma unroll
        for (int ct = 0; ct < 4; ct++)
          acc[rt][ct] = mfma16(af[rt][kk], bfr[ct][kk], acc[rt][ct]);
  }

  // stage to LDS (per-wave region; within-wave dep, no barrier needed)
#pragma unroll
  for (int rt = 0; rt < 2; rt++)
#pragma unroll
    for (int ct = 0; ct < 4; ct++)
#pragma unroll
      for (int jj = 0; jj < 4; jj++) {
        int r = rt * 16 + lg * 4 + jj;
        int cc = ct * 16 + l15;
        sT[w][r * 68 + cc] = acc[rt][ct][jj];
      }
  // read back row-major; each instr: 4 full rows x 256B contiguous stores
#pragma unroll
  for (int i = 0; i < 8; i++) {
    int r = i * 4 + lg;
    int cc = l15 * 4;
    f32x4 v = *(const f32x4*)&sT[w][r * 68 + cc];
    int n = n0 + wc * 64 + cc;
    float4 bv = *(const float4*)(bias + n);
    v[0] += bv.x; v[1] += bv.y; v[2] += bv.z; v[3] += bv.w;
    int m = m0 + wr * 32 + r;
    *(f32x4*)(of + (size_t)m * 1024 + n) = v;
  }
}

// -------------------------------------------------------------- attention ---
// Fused-pair: block = (bh, p) handles q-tiles A=p and B=31-p with ONE K-sweep
// per pass. Balanced p remap; rotation start = bid & 15 (r4). r7/r8:
// LDS-transposed score + zero-strip stores. r9: shared-ak dual-half QK.
//
// THIS REVISION (two isolated compute cuts):
//  1. VECTORIZED ROWSUM ACCUMULATORS (pass 1). Old: rs += exp2(...) x32 --
//     fp adds are NOT reassociable by the compiler, so each iter carried a
//     serial 32-deep v_add_f32 chain (~128cy) that exp2 issue can't hide.
//     New: 16 independent f32x4 slot accumulators per half (1 add/slot/iter),
//     tree-combined once after the sweep.
//  2. SHARED-bv DUAL-HALF PV (pass 2): second P buffer (myPA); one V-fragment
//     b128 read feeds both halves' PV MFMAs (removes 8 of 16 PV reads on
//     dual-active iters). Mirrors r9's proven QK-share.
//
// LDS (64KB pool, 2 blocks/CU):
//   [0,32K):  K buffers. pass1: 4 bufs. pass2: bufs 0-1; [16K,32K) = Sw
//             (4 waves x 4KB f32 staging).
//   [32K,48K): VT 2 bufs (pass2 only).
//   [48K,56K): sPB (4 waves x 2KB bf16 P, B half).
//   [56K,64K): sPA (4 waves x 2KB bf16 P, A half).
//
// vmcnt pass2 (4 GLDS + 8 stores per iter): j==0 [G0(4),G1(4)] -> WV(4);
// steady [G_j(4),S_{j-1}(8),G_{j+1}(4)] -> WV(12); last -> WV(8).
// pass1: steady WV(4), tail WV(2)/WV(0).
__global__ __launch_bounds__(256, 2) void attn_kernel(
    const unsigned short* __restrict__ q_ws,
    const unsigned short* __restrict__ k_ws,
    const unsigned short* __restrict__ v_ws,
    float* __restrict__ scores,
    unsigned short* __restrict__ attn_bf) {
  __shared__ __align__(16) unsigned char smem[65536];

  const int t = threadIdx.x, lane = t & 63, w = t >> 6;
  const int l15 = lane & 15, lg = lane >> 4;
  int bid = blockIdx.x;
  int bh = bid & 31;            // b*16+h
  int pr = bid >> 5;            // 0..15
  int p = (bid < 256) ? pr : (23 - pr);  // balance: bid & bid+256 -> p & 15-p
  int b = bh >> 4, h = bh & 15, kv = h >> 2;
  const int qtA = p, qtB = 31 - p;
  const int NB = qtB + 1;       // 17..32 k-tiles (covers A's p+1)
  const int start = bid & 15;   // == bh & 15: panel-lockstep rotation (r4)

  const unsigned short* Kp = k_ws + ((size_t)(b * 4 + kv) * 2048) * 64;
  const unsigned short* Vp = v_ws + ((size_t)(b * 4 + kv) * 64) * 2048;  // [d][s]
  const int qrA = qtA * 64 + w * 16 + l15;   // this lane's A q-row
  const int qrB = qtB * 64 + w * 16 + l15;   // this lane's B q-row

  auto rot = [&](int j) { int n = j + start; return (n >= NB) ? n - NB : n; };
  auto kbuf = [&](int i) { return (unsigned short*)(smem + i * 8192); };
  auto vbuf = [&](int i) { return (unsigned short*)(smem + 32768 + i * 8192); };
  float* Sw = (float*)(smem + 16384 + w * 4096);       // pass2 f32 staging
  unsigned char* myPB = smem + 49152 + w * 2048;
  unsigned char* myPA = smem + 57344 + w * 2048;

  // per-lane Q fragments (compiler-tracked; FORCE4 drains them before staging)
  bf16x8 aqA[2], aqB[2];
  {
    const unsigned short* qa = q_ws + ((size_t)bh * 2048 + qrA) * 64;
    const unsigned short* qb = q_ws + ((size_t)bh * 2048 + qrB) * 64;
    aqA[0] = *(const bf16x8*)(qa + lg * 8);
    aqA[1] = *(const bf16x8*)(qa + 32 + lg * 8);
    aqB[0] = *(const bf16x8*)(qb + lg * 8);
    aqB[1] = *(const bf16x8*)(qb + 32 + lg * 8);
    FORCE4(*(f32x4*)&aqA[0]); FORCE4(*(f32x4*)&aqA[1]);
    FORCE4(*(f32x4*)&aqB[0]); FORCE4(*(f32x4*)&aqB[1]);
  }

  auto stageK = [&](int kt, int bufi) {  // 2 GLDS per wave
#pragma unroll
    for (int i = 0; i < 2; i++) {
      int idx = i * 256 + w * 64 + lane;
      int row = idx >> 3;
      int cg = (idx & 7) ^ (row & 7);
      GLDS(Kp + (size_t)(kt * 64 + row) * 64 + cg * 8, kbuf(bufi) + (i * 256 + w * 64) * 8);
    }
  };
  auto stageVT = [&](int kt, int bufi) {  // 2 GLDS per wave
#pragma unroll
    for (int i = 0; i < 2; i++) {
      int idx = i * 256 + w * 64 + lane;
      int row = idx >> 3;
      int cg = (idx & 7) ^ (row & 7);
      GLDS(Vp + (size_t)row * 2048 + kt * 64 + cg * 8, vbuf(bufi) + (i * 256 + w * 64) * 8);
    }
  };
  // swapped QK^T: K rows as A, Q as B -> acc[ct][j] = S[q=l15][k0+ct*16+lg*4+j]
  auto qk_tile = [&](const unsigned short* kb, const bf16x8(&aq)[2], f32x4(&acc)[4]) {
#pragma unroll
    for (int ct = 0; ct < 4; ct++) {
      int row = ct * 16 + l15;
#pragma unroll
      for (int kk = 0; kk < 2; kk++) {
        int c = (kk * 4 + lg) ^ (row & 7);
        bf16x8 ak = *(const bf16x8*)((const char*)kb + row * 128 + c * 16);
        acc[ct] = mfma16(ak, aq[kk], acc[ct]);
      }
    }
  };
  // dual-half QK sharing the ak fragment read (both halves active)
  auto qk_tile2 = [&](const unsigned short* kb, f32x4(&accB)[4], f32x4(&accA)[4]) {
#pragma unroll
    for (int ct = 0; ct < 4; ct++) {
      int row = ct * 16 + l15;
#pragma unroll
      for (int kk = 0; kk < 2; kk++) {
        int c = (kk * 4 + lg) ^ (row & 7);
        bf16x8 ak = *(const bf16x8*)((const char*)kb + row * 128 + c * 16);
        accB[ct] = mfma16(ak, aqB[kk], accB[ct]);
        accA[ct] = mfma16(ak, aqA[kk], accA[ct]);
      }
    }
  };
  // LDS-transposed contiguous store of a 16x64 f32 tile.
  auto tstore = [&](float* Sp, const f32x4(&acc)[4], int k0) {
#pragma unroll
    for (int ct = 0; ct < 4; ct++) {
      int xs = (ct * 4 + lg) ^ l15;
      *(f32x4*)(Sw + l15 * 64 + xs * 4) = acc[ct];
    }
#pragma unroll
    for (int i = 0; i < 4; i++) {
      int r = i * 4 + lg;
      int xs = l15 ^ r;
      f32x4 v = *(const f32x4*)(Sw + r * 64 + xs * 4);
      *(f32x4*)(Sp + (size_t)(w * 16 + r) * 2048 + k0 + l15 * 4) = v;
    }
  };

  // ---- pass 1: rowsums for BOTH halves, rotated sweep, 4-buf 2-deep ----
  // 16 independent accumulator slots per half: no serial fp-add chain.
  stageK(rot(0), 0);
  stageK(rot(1), 1);
  f32x4 rsvA[4] = {}, rsvB[4] = {};
  for (int j = 0; j < NB; j++) {
    const int n = rot(j);
    if (j + 2 < NB) { stageK(rot(j + 2), (j + 2) & 3); WV(4); }
    else if (j + 1 < NB) { WV(2); }
    else { WV(0); }
    SBAR();
    const unsigned short* kb = kbuf(j & 3);
    const bool doA = (n <= qtA);
    f32x4 aB4[4] = {}, aA4[4] = {};
    if (doA) { qk_tile2(kb, aB4, aA4); } else { qk_tile(kb, aqB, aB4); }
    if (n < NB - 1) {
#pragma unroll
      for (int ct = 0; ct < 4; ct++)
#pragma unroll
        for (int jj = 0; jj < 4; jj++)
          rsvB[ct][jj] += __builtin_amdgcn_exp2f(aB4[ct][jj]);
    } else {
#pragma unroll
      for (int ct = 0; ct < 4; ct++) {
        int kb0 = n * 64 + ct * 16 + lg * 4;
#pragma unroll
        for (int jj = 0; jj < 4; jj++)
          rsvB[ct][jj] += (kb0 + jj <= qrB) ? __builtin_amdgcn_exp2f(aB4[ct][jj]) : 0.f;
      }
    }
    if (doA) {
      if (n < qtA) {
#pragma unroll
        for (int ct = 0; ct < 4; ct++)
#pragma unroll
          for (int jj = 0; jj < 4; jj++)
            rsvA[ct][jj] += __builtin_amdgcn_exp2f(aA4[ct][jj]);
      } else {
#pragma unroll
        for (int ct = 0; ct < 4; ct++) {
          int kb0 = n * 64 + ct * 16 + lg * 4;
#pragma unroll
          for (int jj = 0; jj < 4; jj++)
            rsvA[ct][jj] += (kb0 + jj <= qrA) ? __builtin_amdgcn_exp2f(aA4[ct][jj]) : 0.f;
        }
      }
    }
    // no bottom barrier: 4-buffer skew (n-1, n, n+2 distinct mod 4)
  }
  f32x4 sB4 = rsvB[0] + rsvB[1];
  sB4 += rsvB[2] + rsvB[3];
  float rsB = (sB4[0] + sB4[1]) + (sB4[2] + sB4[3]);
  f32x4 sA4 = rsvA[0] + rsvA[1];
  sA4 += rsvA[2] + rsvA[3];
  float rsA = (sA4[0] + sA4[1]) + (sA4[2] + sA4[3]);
  rsA += __shfl_xor(rsA, 16); rsA += __shfl_xor(rsA, 32);
  rsB += __shfl_xor(rsB, 16); rsB += __shfl_xor(rsB, 32);
  float rinvA = 1.0f / rsA, rinvB = 1.0f / rsB;

  SBAR();  // pass-1 readers done before pass-2 staging reuses buffers

  // ---- pass 2: transposed P stores + in-loop zeros + shared-bv PV, 2-buf --
  stageK(rot(0), 0); stageVT(rot(0), 0);
  f32x4 accoA[4] = {}, accoB[4] = {};
  const int xr = (l15 & 7) << 4;
  float* SpA = scores + ((size_t)bh * 2048 + qtA * 64) * 2048;
  float* SpB = scores + ((size_t)bh * 2048 + qtB * 64) * 2048;

  for (int j = 0; j < NB; j++) {
    const int n = rot(j);
    if (j + 1 < NB) { stageK(rot(j + 1), (j + 1) & 1); stageVT(rot(j + 1), (j + 1) & 1); }
    if (j == 0) { WV(4); }
    else if (j + 1 < NB) { WV(12); }
    else { WV(8); }
    SBAR();
    const unsigned short* kb = kbuf(j & 1);
    const unsigned short* vt = vbuf(j & 1);
    int k0 = n * 64;
    const bool doA = (n <= qtA);

    f32x4 aB4[4] = {}, aA4[4] = {};
    if (doA) { qk_tile2(kb, aB4, aA4); } else { qk_tile(kb, aqB, aB4); }

    // ---- B half: softmax, transposed store, pack ----
    if (n == NB - 1) {
#pragma unroll
      for (int ct = 0; ct < 4; ct++) {
        int kb0 = k0 + ct * 16 + lg * 4;
#pragma unroll
        for (int jj = 0; jj < 4; jj++)
          aB4[ct][jj] = (kb0 + jj <= qrB) ? __builtin_amdgcn_exp2f(aB4[ct][jj]) * rinvB : 0.f;
      }
    } else {
#pragma unroll
      for (int ct = 0; ct < 4; ct++)
#pragma unroll
        for (int jj = 0; jj < 4; jj++)
          aB4[ct][jj] = __builtin_amdgcn_exp2f(aB4[ct][jj]) * rinvB;
    }
    tstore(SpB, aB4, k0);
#pragma unroll
    for (int ct = 0; ct < 4; ct++) {
      uint2 pw;
      pw.x = cvt_pk(aB4[ct][0], aB4[ct][1]);
      pw.y = cvt_pk(aB4[ct][2], aB4[ct][3]);
      *(uint2*)(myPB + l15 * 128 + ((ct * 32 + lg * 8) ^ xr)) = pw;
    }

    // ---- A half: softmax, transposed store, pack (or zero tile) ----
    if (doA) {
      if (n == qtA) {
#pragma unroll
        for (int ct = 0; ct < 4; ct++) {
          int kb0 = k0 + ct * 16 + lg * 4;
#pragma unroll
          for (int jj = 0; jj < 4; jj++)
            aA4[ct][jj] = (kb0 + jj <= qrA) ? __builtin_amdgcn_exp2f(aA4[ct][jj]) * rinvA : 0.f;
        }
      } else {
#pragma unroll
        for (int ct = 0; ct < 4; ct++)
#pragma unroll
          for (int jj = 0; jj < 4; jj++)
            aA4[ct][jj] = __builtin_amdgcn_exp2f(aA4[ct][jj]) * rinvA;
      }
      tstore(SpA, aA4, k0);
#pragma unroll
      for (int ct = 0; ct < 4; ct++) {
        uint2 pw;
        pw.x = cvt_pk(aA4[ct][0], aA4[ct][1]);
        pw.y = cvt_pk(aA4[ct][2], aA4[ct][3]);
        *(uint2*)(myPA + l15 * 128 + ((ct * 32 + lg * 8) ^ xr)) = pw;
      }
    } else {
      f32x4 z = {0.f, 0.f, 0.f, 0.f};
#pragma unroll
      for (int i = 0; i < 4; i++) {
        int r = i * 4 + lg;
        *(f32x4*)(SpA + (size_t)(w * 16 + r) * 2048 + k0 + l15 * 4) = z;
      }
    }

    // ---- PV: shared bv feeds both halves when A active ----
    if (doA) {
#pragma unroll
      for (int kk = 0; kk < 2; kk++) {
        bf16x8 apB = *(const bf16x8*)(myPB + l15 * 128 + ((kk * 64 + lg * 16) ^ xr));
        bf16x8 apA = *(const bf16x8*)(myPA + l15 * 128 + ((kk * 64 + lg * 16) ^ xr));
#pragma unroll
        for (int ct = 0; ct < 4; ct++) {
          int vrow = ct * 16 + l15;
          int cv = (kk * 4 + lg) ^ (vrow & 7);
          bf16x8 bv = *(const bf16x8*)((const char*)vt + vrow * 128 + cv * 16);
          accoB[ct] = mfma16(bv, apB, accoB[ct]);
          accoA[ct] = mfma16(bv, apA, accoA[ct]);
        }
      }
    } else {
#pragma unroll
      for (int kk = 0; kk < 2; kk++) {
        bf16x8 apB = *(const bf16x8*)(myPB + l15 * 128 + ((kk * 64 + lg * 16) ^ xr));
#pragma unroll
        for (int ct = 0; ct < 4; ct++) {
          int vrow = ct * 16 + l15;
          int cv = (kk * 4 + lg) ^ (vrow & 7);
          bf16x8 bv = *(const bf16x8*)((const char*)vt + vrow * 128 + cv * 16);
          accoB[ct] = mfma16(bv, apB, accoB[ct]);
        }
      }
    }
    SBAR();  // protect 2-buf K/V for next iter's staging
  }

  // O stores: lane holds O[q=l15][d=ct*16+lg*4+..] -> packed uint2
  {
    int mA = b * 2048 + qtA * 64 + w * 16 + l15;
    int mB = b * 2048 + qtB * 64 + w * 16 + l15;
    unsigned int* oA = (unsigned int*)(attn_bf + (size_t)mA * 1024 + h * 64);
    unsigned int* oB = (unsigned int*)(attn_bf + (size_t)mB * 1024 + h * 64);
#pragma unroll
    for (int ct = 0; ct < 4; ct++) {
      uint2 pa, pb;
      pa.x = cvt_pk(accoA[ct][0], accoA[ct][1]);
      pa.y = cvt_pk(accoA[ct][2], accoA[ct][3]);
      pb.x = cvt_pk(accoB[ct][0], accoB[ct][1]);
      pb.y = cvt_pk(accoB[ct][2], accoB[ct][3]);
      *(uint2*)(oA + (ct * 16 + lg * 4) / 2) = pa;
      *(uint2*)(oB + (ct * 16 + lg * 4) / 2) = pb;
    }
  }

  // residual zero strip, transposed shape: cols [NB*64, 2048) for ALL 64
  // rows of both tiles; each instr = 4 complete rows x 256B contiguous.
  int zbase = NB * 64;
  if (zbase < 2048) {
    f32x4 z = {0.f, 0.f, 0.f, 0.f};
    for (int c0 = zbase; c0 < 2048; c0 += 64) {
#pragma unroll
      for (int i = 0; i < 4; i++) {
        int r = i * 4 + lg;
        *(f32x4*)(SpA + (size_t)(w * 16 + r) * 2048 + c0 + l15 * 4) = z;
        *(f32x4*)(SpB + (size_t)(w * 16 + r) * 2048 + c0 + l15 * 4) = z;
      }
    }
  }
}

// ----------------------------------------------------------------- launch ---
extern "C" void kernel_launch(void* const* d_in, const int* in_sizes, int n_in,
                              void* d_out, int out_size, void* d_ws, size_t ws_size,
                              hipStream_t stream) {
  const float* hidden  = (const float*)d_in[0];
  // d_in[1] = mask: causal by construction; applied analytically.
  const float* scaling = (const float*)d_in[2];
  const float* qkv_w   = (const float*)d_in[3];
  const float* qkv_b   = (const float*)d_in[4];
  const float* o_w     = (const float*)d_in[5];
  const float* o_b     = (const float*)d_in[6];

  float* scores = (float*)d_out;                                 // [2][16][2048][2048]
  float* outp   = (float*)d_out + (size_t)2 * 16 * 2048 * 2048;  // [4096][1024]

  char* ws = (char*)d_ws;
  unsigned short* hidden_bf = (unsigned short*)(ws + 0);          //  8 MB
  unsigned short* qkvw_bf   = (unsigned short*)(ws + 8388608);    //  3 MB
  unsigned short* ow_bf     = (unsigned short*)(ws + 11534336);   //  2 MB
  unsigned short* q_ws      = (unsigned short*)(ws + 13631488);   //  8 MB
  unsigned short* k_ws      = (unsigned short*)(ws + 22020096);   //  2 MB
  unsigned short* v_ws      = (unsigned short*)(ws + 24117248);   //  2 MB
  unsigned short* attn_bf   = (unsigned short*)(ws + 26214400);   //  8 MB
  float* qscale             = (float*)(ws + 34603008);            //  256 B

  convert_kernel<<<512, 256, 0, stream>>>(hidden, qkv_w, o_w, scaling,
                                          hidden_bf, qkvw_bf, ow_bf, qscale);
  gemm_kernel<<<dim3(8, 64), 256, 0, stream>>>(hidden_bf, qkvw_bf, qkv_b,
                                               qscale, q_ws, k_ws, v_ws);
  attn_kernel<<<512, 256, 0, stream>>>(q_ws, k_ws, v_ws, scores, attn_bf);
  gemm2_kernel<<<dim3(8, 64), 256, 0, stream>>>(attn_bf, ow_bf, o_b, outp);
}

// Round 12
// 182.576 us; speedup vs baseline: 1.0112x; 1.0112x over previous
//
#include <hip/hip_runtime.h>
#include <hip/hip_bf16.h>
#include <cstdint>
#include <cstddef>

typedef __attribute__((ext_vector_type(4))) float f32x4;
typedef __attribute__((ext_vector_type(8))) short bf16x8;

#define DEVI static __device__ __forceinline__

DEVI unsigned short f2bf(float f) {
  union { float f; unsigned int u; } v; v.f = f;
  unsigned int u = v.u;
  unsigned int r = (u + 0x7fffu + ((u >> 16) & 1u)) >> 16;
  return (unsigned short)r;
}

// packed fp32 pair -> bf16x2 in one VALU op (RNE)
DEVI unsigned int cvt_pk(float lo, float hi) {
  unsigned int r;
  asm("v_cvt_pk_bf16_f32 %0, %1, %2" : "=v"(r) : "v"(lo), "v"(hi));
  return r;
}

DEVI f32x4 mfma16(bf16x8 a, bf16x8 b, f32x4 c) {
  return __builtin_amdgcn_mfma_f32_16x16x32_bf16(a, b, c, 0, 0, 0);
}

// global -> LDS direct staging, 16B per lane (wave-uniform LDS base).
#define GLDS(gp, lp) __builtin_amdgcn_global_load_lds(                         \
    (const __attribute__((address_space(1))) void*)(const void*)(gp),          \
    (__attribute__((address_space(3))) void*)(void*)(lp), 16, 0, 0)

#define SBAR() asm volatile("s_barrier" ::: "memory")
#define WV(n) asm volatile("s_waitcnt vmcnt(" #n ")" ::: "memory")
#define FORCE4(x) asm volatile("" : "+v"(x))

// ---------------------------------------------------------------- convert ---
__global__ void convert_kernel(const float* __restrict__ hidden,
                               const float* __restrict__ qkv_w,
                               const float* __restrict__ o_w,
                               const float* __restrict__ scaling,
                               unsigned short* __restrict__ hbf,
                               unsigned short* __restrict__ wbf,
                               unsigned short* __restrict__ obf,
                               float* __restrict__ qscale) {
  int tid = blockIdx.x * blockDim.x + threadIdx.x;
  int nt = gridDim.x * blockDim.x;
  if (tid < 64) {
    float x = scaling[tid];
    float sp = (x > 20.f) ? x : log1pf(__expf(x));
    // (1.442695041/8)*softplus, times log2e so softmax can use exp2 directly.
    qscale[tid] = 0.1803368801243369f * 1.4426950408889634f * sp;
  }
  for (int i = tid; i < 1048576; i += nt) {
    float4 v = ((const float4*)hidden)[i];
    ushort4 o = { f2bf(v.x), f2bf(v.y), f2bf(v.z), f2bf(v.w) };
    ((ushort4*)hbf)[i] = o;
  }
  for (int i = tid; i < 393216; i += nt) {
    float4 v = ((const float4*)qkv_w)[i];
    ushort4 o = { f2bf(v.x), f2bf(v.y), f2bf(v.z), f2bf(v.w) };
    ((ushort4*)wbf)[i] = o;
  }
  for (int i = tid; i < 262144; i += nt) {
    float4 v = ((const float4*)o_w)[i];
    ushort4 o = { f2bf(v.x), f2bf(v.y), f2bf(v.z), f2bf(v.w) };
    ((ushort4*)obf)[i] = o;
  }
}

// ------------------------------------------------------ GEMM 1 (qkv proj) ---
// 64x192 tiles -> grid (8,64) = 512 UNIFORM blocks = exactly 2 blocks/CU
// (r9). 4 waves: wave w owns all 64 rows x cols [w*48, w*48+48).
__global__ __launch_bounds__(256, 2) void gemm_kernel(
    const unsigned short* __restrict__ A,
    const unsigned short* __restrict__ Bw,
    const float* __restrict__ bias,
    const float* __restrict__ qscale,
    unsigned short* __restrict__ oq,
    unsigned short* __restrict__ okv,
    unsigned short* __restrict__ ovt) {
  __shared__ __align__(16) unsigned short sA[64 * 64];
  __shared__ __align__(16) unsigned short sB[192 * 64];
  const int t = threadIdx.x, lane = t & 63, w = t >> 6;
  const int l15 = lane & 15, lg = lane >> 4;
  const int m0 = blockIdx.y * 64, n0 = blockIdx.x * 192;

  f32x4 acc[4][3] = {};

  for (int kb = 0; kb < 1024; kb += 64) {
    __syncthreads();
#pragma unroll
    for (int i = 0; i < 2; i++) {
      int idx = i * 256 + w * 64 + lane;
      int row = idx >> 3;
      int cg = (idx & 7) ^ (row & 7);
      GLDS(A + (size_t)(m0 + row) * 1024 + kb + cg * 8, sA + (i * 256 + w * 64) * 8);
    }
#pragma unroll
    for (int i = 0; i < 6; i++) {
      int idx = i * 256 + w * 64 + lane;
      int row = idx >> 3;
      int cg = (idx & 7) ^ (row & 7);
      GLDS(Bw + (size_t)(n0 + row) * 1024 + kb + cg * 8, sB + (i * 256 + w * 64) * 8);
    }
    __syncthreads();
    bf16x8 af[4][2], bfr[3][2];
#pragma unroll
    for (int rt = 0; rt < 4; rt++) {
      int row = rt * 16 + l15;
#pragma unroll
      for (int kk = 0; kk < 2; kk++) {
        int c = (kk * 4 + lg) ^ (row & 7);
        af[rt][kk] = *(const bf16x8*)((const char*)sA + row * 128 + c * 16);
      }
    }
#pragma unroll
    for (int ct = 0; ct < 3; ct++) {
      int rowb = w * 48 + ct * 16 + l15;
#pragma unroll
      for (int kk = 0; kk < 2; kk++) {
        int c = (kk * 4 + lg) ^ (rowb & 7);
        bfr[ct][kk] = *(const bf16x8*)((const char*)sB + rowb * 128 + c * 16);
      }
    }
#pragma unroll
    for (int kk = 0; kk < 2; kk++)
#pragma unroll
      for (int rt = 0; rt < 4; rt++)
#pragma unroll
        for (int ct = 0; ct < 3; ct++)
          acc[rt][ct] = mfma16(af[rt][kk], bfr[ct][kk], acc[rt][ct]);
  }

#pragma unroll
  for (int rt = 0; rt < 4; rt++) {
#pragma unroll
    for (int ct = 0; ct < 3; ct++) {
      int n = n0 + w * 48 + ct * 16 + l15;
      float bv = bias[n];
#pragma unroll
      for (int jj = 0; jj < 4; jj++) {
        int m = m0 + rt * 16 + lg * 4 + jj;
        float v = acc[rt][ct][jj] + bv;
        int b = m >> 11, s = m & 2047;
        if (n < 1024) {  // q: scaled, [b][h][s][d]
          int h = n >> 6, d = n & 63;
          v *= qscale[d];
          oq[(((size_t)(b * 16 + h) * 2048 + s) << 6) + d] = f2bf(v);
        } else if (n < 1280) {  // k: [b][kv][s][d]
          int kv = (n - 1024) >> 6, d = n & 63;
          okv[(((size_t)(b * 4 + kv) * 2048 + s) << 6) + d] = f2bf(v);
        } else {  // v transposed: [b][kv][d][s]
          int kv = (n - 1280) >> 6, d = n & 63;
          ovt[(((size_t)((b * 4 + kv) * 64 + d)) << 11) + s] = f2bf(v);
        }
      }
    }
  }
}

// ----------------------------------------------------- GEMM 2 (out proj) ----
// 64x128 tile -> grid (8,64) = 512 blocks = 2 blocks/CU. Transposed epilogue
// (r8): stage 32x64 f32 sub-tile in LDS (stride-68), store 4 full rows x
// 256B contiguous per instruction.
__global__ __launch_bounds__(256, 2) void gemm2_kernel(
    const unsigned short* __restrict__ A,    // [4096][1024] bf16
    const unsigned short* __restrict__ Bw,   // [1024][1024] bf16 (o_w)
    const float* __restrict__ bias,
    float* __restrict__ of) {
  __shared__ __align__(16) unsigned short sA[64 * 64];
  __shared__ __align__(16) unsigned short sB[128 * 64];
  __shared__ __align__(16) float sT[4][32 * 68];
  const int t = threadIdx.x, lane = t & 63, w = t >> 6;
  const int l15 = lane & 15, lg = lane >> 4;
  const int m0 = blockIdx.y * 64, n0 = blockIdx.x * 128;
  const int wr = w >> 1, wc = w & 1;  // 2x2 wave grid over 64x128

  f32x4 acc[2][4] = {};

  for (int kb = 0; kb < 1024; kb += 64) {
    __syncthreads();
#pragma unroll
    for (int i = 0; i < 2; i++) {
      int idx = i * 256 + w * 64 + lane;
      int row = idx >> 3;
      int cg = (idx & 7) ^ (row & 7);
      GLDS(A + (size_t)(m0 + row) * 1024 + kb + cg * 8, sA + (i * 256 + w * 64) * 8);
    }
#pragma unroll
    for (int i = 0; i < 4; i++) {
      int idx = i * 256 + w * 64 + lane;
      int row = idx >> 3;
      int cg = (idx & 7) ^ (row & 7);
      GLDS(Bw + (size_t)(n0 + row) * 1024 + kb + cg * 8, sB + (i * 256 + w * 64) * 8);
    }
    __syncthreads();
    bf16x8 af[2][2], bfr[4][2];
#pragma unroll
    for (int rt = 0; rt < 2; rt++) {
      int row = wr * 32 + rt * 16 + l15;
#pragma unroll
      for (int kk = 0; kk < 2; kk++) {
        int c = (kk * 4 + lg) ^ (row & 7);
        af[rt][kk] = *(const bf16x8*)((const char*)sA + row * 128 + c * 16);
      }
    }
#pragma unroll
    for (int ct = 0; ct < 4; ct++) {
      int rowb = wc * 64 + ct * 16 + l15;
#pragma unroll
      for (int kk = 0; kk < 2; kk++) {
        int c = (kk * 4 + lg) ^ (rowb & 7);
        bfr[ct][kk] = *(const bf16x8*)((const char*)sB + rowb * 128 + c * 16);
      }
    }
#pragma unroll
    for (int kk = 0; kk < 2; kk++)
#pragma unroll
      for (int rt = 0; rt < 2; rt++)
#pragma unroll
        for (int ct = 0; ct < 4; ct++)
          acc[rt][ct] = mfma16(af[rt][kk], bfr[ct][kk], acc[rt][ct]);
  }

  // stage to LDS (per-wave region; within-wave dep, no barrier needed)
#pragma unroll
  for (int rt = 0; rt < 2; rt++)
#pragma unroll
    for (int ct = 0; ct < 4; ct++)
#pragma unroll
      for (int jj = 0; jj < 4; jj++) {
        int r = rt * 16 + lg * 4 + jj;
        int cc = ct * 16 + l15;
        sT[w][r * 68 + cc] = acc[rt][ct][jj];
      }
  // read back row-major; each instr: 4 full rows x 256B contiguous stores
#pragma unroll
  for (int i = 0; i < 8; i++) {
    int r = i * 4 + lg;
    int cc = l15 * 4;
    f32x4 v = *(const f32x4*)&sT[w][r * 68 + cc];
    int n = n0 + wc * 64 + cc;
    float4 bv = *(const float4*)(bias + n);
    v[0] += bv.x; v[1] += bv.y; v[2] += bv.z; v[3] += bv.w;
    int m = m0 + wr * 32 + r;
    *(f32x4*)(of + (size_t)m * 1024 + n) = v;
  }
}

// -------------------------------------------------------------- attention ---
// Fused-pair: block = (bh, p) handles q-tiles A=p and B=31-p with ONE K-sweep
// per pass. Balanced p remap; rotation start = bid & 15 (r4). r7/r8:
// LDS-transposed score + zero-strip stores. r9: shared-ak dual-half QK.
// r10 post-mortem: PV-share + 2nd P buffer was neutral-negative -> reverted
// (PV LDS reads are latency-hidden, unlike QK's which feed a dep chain).
// Vectorized rowsum accumulators kept (sound: removes the serial 32-deep
// non-reassociable fp-add chain).
//
// THIS REVISION: NORMALIZATION FOLDED INTO THE MFMA ACCUMULATOR (pass 2).
// p = exp2(s)*rinv = exp2(s + log2(rinv)). Init the QK accumulator C to
// lrinv = -log2(rowsum) instead of 0 -> the add is FREE (MFMA computes
// A*B+C), deleting all 32 v_mul_f32 per dual-iter per wave + tail muls.
// One v_log_f32 per half per block. Masked lanes still write exact 0.
//
// LDS (56KB pool, 2 blocks/CU):
//   [0,32K):  K buffers. pass1: 4 bufs (2-deep prefetch, 1 barrier/iter).
//             pass2: bufs 0-1; [16K,32K) = Sw (4 waves x 4KB f32 staging).
//   [32K,48K): VT 2 bufs (pass2 only).
//   [48K,56K): sP (4 waves x 2KB bf16 P).
//
// vmcnt pass2 (4 GLDS + 8 stores per iter): j==0 [G0(4),G1(4)] -> WV(4);
// steady [G_j(4),S_{j-1}(8),G_{j+1}(4)] -> WV(12); last -> WV(8).
// pass1: steady WV(4), tail WV(2)/WV(0).
__global__ __launch_bounds__(256, 2) void attn_kernel(
    const unsigned short* __restrict__ q_ws,
    const unsigned short* __restrict__ k_ws,
    const unsigned short* __restrict__ v_ws,
    float* __restrict__ scores,
    unsigned short* __restrict__ attn_bf) {
  __shared__ __align__(16) unsigned char smem[57344];

  const int t = threadIdx.x, lane = t & 63, w = t >> 6;
  const int l15 = lane & 15, lg = lane >> 4;
  int bid = blockIdx.x;
  int bh = bid & 31;            // b*16+h
  int pr = bid >> 5;            // 0..15
  int p = (bid < 256) ? pr : (23 - pr);  // balance: bid & bid+256 -> p & 15-p
  int b = bh >> 4, h = bh & 15, kv = h >> 2;
  const int qtA = p, qtB = 31 - p;
  const int NB = qtB + 1;       // 17..32 k-tiles (covers A's p+1)
  const int start = bid & 15;   // == bh & 15: panel-lockstep rotation (r4)

  const unsigned short* Kp = k_ws + ((size_t)(b * 4 + kv) * 2048) * 64;
  const unsigned short* Vp = v_ws + ((size_t)(b * 4 + kv) * 64) * 2048;  // [d][s]
  const int qrA = qtA * 64 + w * 16 + l15;   // this lane's A q-row
  const int qrB = qtB * 64 + w * 16 + l15;   // this lane's B q-row

  auto rot = [&](int j) { int n = j + start; return (n >= NB) ? n - NB : n; };
  auto kbuf = [&](int i) { return (unsigned short*)(smem + i * 8192); };
  auto vbuf = [&](int i) { return (unsigned short*)(smem + 32768 + i * 8192); };
  float* Sw = (float*)(smem + 16384 + w * 4096);       // pass2 f32 staging
  unsigned char* myP = smem + 49152 + w * 2048;

  // per-lane Q fragments (compiler-tracked; FORCE4 drains them before staging)
  bf16x8 aqA[2], aqB[2];
  {
    const unsigned short* qa = q_ws + ((size_t)bh * 2048 + qrA) * 64;
    const unsigned short* qb = q_ws + ((size_t)bh * 2048 + qrB) * 64;
    aqA[0] = *(const bf16x8*)(qa + lg * 8);
    aqA[1] = *(const bf16x8*)(qa + 32 + lg * 8);
    aqB[0] = *(const bf16x8*)(qb + lg * 8);
    aqB[1] = *(const bf16x8*)(qb + 32 + lg * 8);
    FORCE4(*(f32x4*)&aqA[0]); FORCE4(*(f32x4*)&aqA[1]);
    FORCE4(*(f32x4*)&aqB[0]); FORCE4(*(f32x4*)&aqB[1]);
  }

  auto stageK = [&](int kt, int bufi) {  // 2 GLDS per wave
#pragma unroll
    for (int i = 0; i < 2; i++) {
      int idx = i * 256 + w * 64 + lane;
      int row = idx >> 3;
      int cg = (idx & 7) ^ (row & 7);
      GLDS(Kp + (size_t)(kt * 64 + row) * 64 + cg * 8, kbuf(bufi) + (i * 256 + w * 64) * 8);
    }
  };
  auto stageVT = [&](int kt, int bufi) {  // 2 GLDS per wave
#pragma unroll
    for (int i = 0; i < 2; i++) {
      int idx = i * 256 + w * 64 + lane;
      int row = idx >> 3;
      int cg = (idx & 7) ^ (row & 7);
      GLDS(Vp + (size_t)row * 2048 + kt * 64 + cg * 8, vbuf(bufi) + (i * 256 + w * 64) * 8);
    }
  };
  // swapped QK^T: K rows as A, Q as B -> acc[ct][j] = S[q=l15][k0+ct*16+lg*4+j]
  auto qk_tile = [&](const unsigned short* kb, const bf16x8(&aq)[2], f32x4(&acc)[4]) {
#pragma unroll
    for (int ct = 0; ct < 4; ct++) {
      int row = ct * 16 + l15;
#pragma unroll
      for (int kk = 0; kk < 2; kk++) {
        int c = (kk * 4 + lg) ^ (row & 7);
        bf16x8 ak = *(const bf16x8*)((const char*)kb + row * 128 + c * 16);
        acc[ct] = mfma16(ak, aq[kk], acc[ct]);
      }
    }
  };
  // dual-half QK sharing the ak fragment read (both halves active)
  auto qk_tile2 = [&](const unsigned short* kb, f32x4(&accB)[4], f32x4(&accA)[4]) {
#pragma unroll
    for (int ct = 0; ct < 4; ct++) {
      int row = ct * 16 + l15;
#pragma unroll
      for (int kk = 0; kk < 2; kk++) {
        int c = (kk * 4 + lg) ^ (row & 7);
        bf16x8 ak = *(const bf16x8*)((const char*)kb + row * 128 + c * 16);
        accB[ct] = mfma16(ak, aqB[kk], accB[ct]);
        accA[ct] = mfma16(ak, aqA[kk], accA[ct]);
      }
    }
  };
  // LDS-transposed contiguous store of a 16x64 f32 tile.
  auto tstore = [&](float* Sp, const f32x4(&acc)[4], int k0) {
#pragma unroll
    for (int ct = 0; ct < 4; ct++) {
      int xs = (ct * 4 + lg) ^ l15;
      *(f32x4*)(Sw + l15 * 64 + xs * 4) = acc[ct];
    }
#pragma unroll
    for (int i = 0; i < 4; i++) {
      int r = i * 4 + lg;
      int xs = l15 ^ r;
      f32x4 v = *(const f32x4*)(Sw + r * 64 + xs * 4);
      *(f32x4*)(Sp + (size_t)(w * 16 + r) * 2048 + k0 + l15 * 4) = v;
    }
  };

  // ---- pass 1: rowsums for BOTH halves, rotated sweep, 4-buf 2-deep ----
  // 16 independent accumulator slots per half: no serial fp-add chain.
  stageK(rot(0), 0);
  stageK(rot(1), 1);
  f32x4 rsvA[4] = {}, rsvB[4] = {};
  for (int j = 0; j < NB; j++) {
    const int n = rot(j);
    if (j + 2 < NB) { stageK(rot(j + 2), (j + 2) & 3); WV(4); }
    else if (j + 1 < NB) { WV(2); }
    else { WV(0); }
    SBAR();
    const unsigned short* kb = kbuf(j & 3);
    const bool doA = (n <= qtA);
    f32x4 aB4[4] = {}, aA4[4] = {};
    if (doA) { qk_tile2(kb, aB4, aA4); } else { qk_tile(kb, aqB, aB4); }
    if (n < NB - 1) {
#pragma unroll
      for (int ct = 0; ct < 4; ct++)
#pragma unroll
        for (int jj = 0; jj < 4; jj++)
          rsvB[ct][jj] += __builtin_amdgcn_exp2f(aB4[ct][jj]);
    } else {
#pragma unroll
      for (int ct = 0; ct < 4; ct++) {
        int kb0 = n * 64 + ct * 16 + lg * 4;
#pragma unroll
        for (int jj = 0; jj < 4; jj++)
          rsvB[ct][jj] += (kb0 + jj <= qrB) ? __builtin_amdgcn_exp2f(aB4[ct][jj]) : 0.f;
      }
    }
    if (doA) {
      if (n < qtA) {
#pragma unroll
        for (int ct = 0; ct < 4; ct++)
#pragma unroll
          for (int jj = 0; jj < 4; jj++)
            rsvA[ct][jj] += __builtin_amdgcn_exp2f(aA4[ct][jj]);
      } else {
#pragma unroll
        for (int ct = 0; ct < 4; ct++) {
          int kb0 = n * 64 + ct * 16 + lg * 4;
#pragma unroll
          for (int jj = 0; jj < 4; jj++)
            rsvA[ct][jj] += (kb0 + jj <= qrA) ? __builtin_amdgcn_exp2f(aA4[ct][jj]) : 0.f;
        }
      }
    }
    // no bottom barrier: 4-buffer skew (n-1, n, n+2 distinct mod 4)
  }
  f32x4 sB4 = rsvB[0] + rsvB[1];
  sB4 += rsvB[2] + rsvB[3];
  float rsB = (sB4[0] + sB4[1]) + (sB4[2] + sB4[3]);
  f32x4 sA4 = rsvA[0] + rsvA[1];
  sA4 += rsvA[2] + rsvA[3];
  float rsA = (sA4[0] + sA4[1]) + (sA4[2] + sA4[3]);
  rsA += __shfl_xor(rsA, 16); rsA += __shfl_xor(rsA, 32);
  rsB += __shfl_xor(rsB, 16); rsB += __shfl_xor(rsB, 32);
  // fold normalization into exp2: p = exp2(s + lr), lr = -log2(rowsum)
  float lrA = -__log2f(rsA), lrB = -__log2f(rsB);

  SBAR();  // pass-1 readers done before pass-2 staging reuses buffers

  // ---- pass 2: transposed P stores + in-loop zeros + PV, 2-buf ----
  stageK(rot(0), 0); stageVT(rot(0), 0);
  f32x4 accoA[4] = {}, accoB[4] = {};
  const int xr = (l15 & 7) << 4;
  float* SpA = scores + ((size_t)bh * 2048 + qtA * 64) * 2048;
  float* SpB = scores + ((size_t)bh * 2048 + qtB * 64) * 2048;
  const f32x4 initB = {lrB, lrB, lrB, lrB};
  const f32x4 initA = {lrA, lrA, lrA, lrA};

  for (int j = 0; j < NB; j++) {
    const int n = rot(j);
    if (j + 1 < NB) { stageK(rot(j + 1), (j + 1) & 1); stageVT(rot(j + 1), (j + 1) & 1); }
    if (j == 0) { WV(4); }
    else if (j + 1 < NB) { WV(12); }
    else { WV(8); }
    SBAR();
    const unsigned short* kb = kbuf(j & 1);
    const unsigned short* vt = vbuf(j & 1);
    int k0 = n * 64;
    const bool doA = (n <= qtA);

    // QK with lrinv pre-loaded in the accumulator (the add is free)
    f32x4 aB4[4] = {initB, initB, initB, initB};
    f32x4 aA4[4] = {initA, initA, initA, initA};
    if (doA) { qk_tile2(kb, aB4, aA4); } else { qk_tile(kb, aqB, aB4); }

    // ---- B half: softmax (no muls), transposed store, pack, PV ----
    {
      if (n == NB - 1) {
#pragma unroll
        for (int ct = 0; ct < 4; ct++) {
          int kb0 = k0 + ct * 16 + lg * 4;
#pragma unroll
          for (int jj = 0; jj < 4; jj++)
            aB4[ct][jj] = (kb0 + jj <= qrB) ? __builtin_amdgcn_exp2f(aB4[ct][jj]) : 0.f;
        }
      } else {
#pragma unroll
        for (int ct = 0; ct < 4; ct++)
#pragma unroll
          for (int jj = 0; jj < 4; jj++)
            aB4[ct][jj] = __builtin_amdgcn_exp2f(aB4[ct][jj]);
      }
      tstore(SpB, aB4, k0);
#pragma unroll
      for (int ct = 0; ct < 4; ct++) {
        uint2 pw;
        pw.x = cvt_pk(aB4[ct][0], aB4[ct][1]);
        pw.y = cvt_pk(aB4[ct][2], aB4[ct][3]);
        *(uint2*)(myP + l15 * 128 + ((ct * 32 + lg * 8) ^ xr)) = pw;
      }
#pragma unroll
      for (int kk = 0; kk < 2; kk++) {
        bf16x8 ap = *(const bf16x8*)(myP + l15 * 128 + ((kk * 64 + lg * 16) ^ xr));
#pragma unroll
        for (int ct = 0; ct < 4; ct++) {
          int vrow = ct * 16 + l15;
          int cv = (kk * 4 + lg) ^ (vrow & 7);
          bf16x8 bv = *(const bf16x8*)((const char*)vt + vrow * 128 + cv * 16);
          accoB[ct] = mfma16(bv, ap, accoB[ct]);
        }
      }
    }

    // ---- A half (or transposed-pattern zero tile) ----
    if (doA) {
      if (n == qtA) {
#pragma unroll
        for (int ct = 0; ct < 4; ct++) {
          int kb0 = k0 + ct * 16 + lg * 4;
#pragma unroll
          for (int jj = 0; jj < 4; jj++)
            aA4[ct][jj] = (kb0 + jj <= qrA) ? __builtin_amdgcn_exp2f(aA4[ct][jj]) : 0.f;
        }
      } else {
#pragma unroll
        for (int ct = 0; ct < 4; ct++)
#pragma unroll
          for (int jj = 0; jj < 4; jj++)
            aA4[ct][jj] = __builtin_amdgcn_exp2f(aA4[ct][jj]);
      }
      tstore(SpA, aA4, k0);
#pragma unroll
      for (int ct = 0; ct < 4; ct++) {
        uint2 pw;
        pw.x = cvt_pk(aA4[ct][0], aA4[ct][1]);
        pw.y = cvt_pk(aA4[ct][2], aA4[ct][3]);
        *(uint2*)(myP + l15 * 128 + ((ct * 32 + lg * 8) ^ xr)) = pw;
      }
#pragma unroll
      for (int kk = 0; kk < 2; kk++) {
        bf16x8 ap = *(const bf16x8*)(myP + l15 * 128 + ((kk * 64 + lg * 16) ^ xr));
#pragma unroll
        for (int ct = 0; ct < 4; ct++) {
          int vrow = ct * 16 + l15;
          int cv = (kk * 4 + lg) ^ (vrow & 7);
          bf16x8 bv = *(const bf16x8*)((const char*)vt + vrow * 128 + cv * 16);
          accoA[ct] = mfma16(bv, ap, accoA[ct]);
        }
      }
    } else {
      f32x4 z = {0.f, 0.f, 0.f, 0.f};
#pragma unroll
      for (int i = 0; i < 4; i++) {
        int r = i * 4 + lg;
        *(f32x4*)(SpA + (size_t)(w * 16 + r) * 2048 + k0 + l15 * 4) = z;
      }
    }
    SBAR();  // protect 2-buf K/V for next iter's staging
  }

  // O stores: lane holds O[q=l15][d=ct*16+lg*4+..] -> packed uint2
  {
    int mA = b * 2048 + qtA * 64 + w * 16 + l15;
    int mB = b * 2048 + qtB * 64 + w * 16 + l15;
    unsigned int* oA = (unsigned int*)(attn_bf + (size_t)mA * 1024 + h * 64);
    unsigned int* oB = (unsigned int*)(attn_bf + (size_t)mB * 1024 + h * 64);
#pragma unroll
    for (int ct = 0; ct < 4; ct++) {
      uint2 pa, pb;
      pa.x = cvt_pk(accoA[ct][0], accoA[ct][1]);
      pa.y = cvt_pk(accoA[ct][2], accoA[ct][3]);
      pb.x = cvt_pk(accoB[ct][0], accoB[ct][1]);
      pb.y = cvt_pk(accoB[ct][2], accoB[ct][3]);
      *(uint2*)(oA + (ct * 16 + lg * 4) / 2) = pa;
      *(uint2*)(oB + (ct * 16 + lg * 4) / 2) = pb;
    }
  }

  // residual zero strip, transposed shape: cols [NB*64, 2048) for ALL 64
  // rows of both tiles; each instr = 4 complete rows x 256B contiguous.
  int zbase = NB * 64;
  if (zbase < 2048) {
    f32x4 z = {0.f, 0.f, 0.f, 0.f};
    for (int c0 = zbase; c0 < 2048; c0 += 64) {
#pragma unroll
      for (int i = 0; i < 4; i++) {
        int r = i * 4 + lg;
        *(f32x4*)(SpA + (size_t)(w * 16 + r) * 2048 + c0 + l15 * 4) = z;
        *(f32x4*)(SpB + (size_t)(w * 16 + r) * 2048 + c0 + l15 * 4) = z;
      }
    }
  }
}

// ----------------------------------------------------------------- launch ---
extern "C" void kernel_launch(void* const* d_in, const int* in_sizes, int n_in,
                              void* d_out, int out_size, void* d_ws, size_t ws_size,
                              hipStream_t stream) {
  const float* hidden  = (const float*)d_in[0];
  // d_in[1] = mask: causal by construction; applied analytically.
  const float* scaling = (const float*)d_in[2];
  const float* qkv_w   = (const float*)d_in[3];
  const float* qkv_b   = (const float*)d_in[4];
  const float* o_w     = (const float*)d_in[5];
  const float* o_b     = (const float*)d_in[6];

  float* scores = (float*)d_out;                                 // [2][16][2048][2048]
  float* outp   = (float*)d_out + (size_t)2 * 16 * 2048 * 2048;  // [4096][1024]

  char* ws = (char*)d_ws;
  unsigned short* hidden_bf = (unsigned short*)(ws + 0);          //  8 MB
  unsigned short* qkvw_bf   = (unsigned short*)(ws + 8388608);    //  3 MB
  unsigned short* ow_bf     = (unsigned short*)(ws + 11534336);   //  2 MB
  unsigned short* q_ws      = (unsigned short*)(ws + 13631488);   //  8 MB
  unsigned short* k_ws      = (unsigned short*)(ws + 22020096);   //  2 MB
  unsigned short* v_ws      = (unsigned short*)(ws + 24117248);   //  2 MB
  unsigned short* attn_bf   = (unsigned short*)(ws + 26214400);   //  8 MB
  float* qscale             = (float*)(ws + 34603008);            //  256 B

  convert_kernel<<<512, 256, 0, stream>>>(hidden, qkv_w, o_w, scaling,
                                          hidden_bf, qkvw_bf, ow_bf, qscale);
  gemm_kernel<<<dim3(8, 64), 256, 0, stream>>>(hidden_bf, qkvw_bf, qkv_b,
                                               qscale, q_ws, k_ws, v_ws);
  attn_kernel<<<512, 256, 0, stream>>>(q_ws, k_ws, v_ws, scores, attn_bf);
  gemm2_kernel<<<dim3(8, 64), 256, 0, stream>>>(attn_bf, ow_bf, o_b, outp);
}

// Round 13
// 174.762 us; speedup vs baseline: 1.0564x; 1.0447x over previous
//
#include <hip/hip_runtime.h>
#include <hip/hip_bf16.h>
#include <cstdint>
#include <cstddef>

typedef __attribute__((ext_vector_type(4))) float f32x4;
typedef __attribute__((ext_vector_type(8))) short bf16x8;

#define DEVI static __device__ __forceinline__

DEVI unsigned short f2bf(float f) {
  union { float f; unsigned int u; } v; v.f = f;
  unsigned int u = v.u;
  unsigned int r = (u + 0x7fffu + ((u >> 16) & 1u)) >> 16;
  return (unsigned short)r;
}

// packed fp32 pair -> bf16x2 in one VALU op (RNE)
DEVI unsigned int cvt_pk(float lo, float hi) {
  unsigned int r;
  asm("v_cvt_pk_bf16_f32 %0, %1, %2" : "=v"(r) : "v"(lo), "v"(hi));
  return r;
}

DEVI f32x4 mfma16(bf16x8 a, bf16x8 b, f32x4 c) {
  return __builtin_amdgcn_mfma_f32_16x16x32_bf16(a, b, c, 0, 0, 0);
}

// global -> LDS direct staging, 16B per lane (wave-uniform LDS base).
#define GLDS(gp, lp) __builtin_amdgcn_global_load_lds(                         \
    (const __attribute__((address_space(1))) void*)(const void*)(gp),          \
    (__attribute__((address_space(3))) void*)(void*)(lp), 16, 0, 0)

#define SBAR() asm volatile("s_barrier" ::: "memory")
#define WV(n) asm volatile("s_waitcnt vmcnt(" #n ")" ::: "memory")
#define FORCE4(x) asm volatile("" : "+v"(x))

// ---------------------------------------------------------------- convert ---
__global__ void convert_kernel(const float* __restrict__ hidden,
                               const float* __restrict__ qkv_w,
                               const float* __restrict__ o_w,
                               const float* __restrict__ scaling,
                               unsigned short* __restrict__ hbf,
                               unsigned short* __restrict__ wbf,
                               unsigned short* __restrict__ obf,
                               float* __restrict__ qscale) {
  int tid = blockIdx.x * blockDim.x + threadIdx.x;
  int nt = gridDim.x * blockDim.x;
  if (tid < 64) {
    float x = scaling[tid];
    float sp = (x > 20.f) ? x : log1pf(__expf(x));
    // (1.442695041/8)*softplus, times log2e so softmax can use exp2 directly.
    qscale[tid] = 0.1803368801243369f * 1.4426950408889634f * sp;
  }
  for (int i = tid; i < 1048576; i += nt) {
    float4 v = ((const float4*)hidden)[i];
    ushort4 o = { f2bf(v.x), f2bf(v.y), f2bf(v.z), f2bf(v.w) };
    ((ushort4*)hbf)[i] = o;
  }
  for (int i = tid; i < 393216; i += nt) {
    float4 v = ((const float4*)qkv_w)[i];
    ushort4 o = { f2bf(v.x), f2bf(v.y), f2bf(v.z), f2bf(v.w) };
    ((ushort4*)wbf)[i] = o;
  }
  for (int i = tid; i < 262144; i += nt) {
    float4 v = ((const float4*)o_w)[i];
    ushort4 o = { f2bf(v.x), f2bf(v.y), f2bf(v.z), f2bf(v.w) };
    ((ushort4*)obf)[i] = o;
  }
}

// ------------------------------------------------------ GEMM 1 (qkv proj) ---
// 64x192 tiles -> grid (8,64) = 512 UNIFORM blocks = exactly 2 blocks/CU
// (r9). 4 waves: wave w owns all 64 rows x cols [w*48, w*48+48).
__global__ __launch_bounds__(256, 2) void gemm_kernel(
    const unsigned short* __restrict__ A,
    const unsigned short* __restrict__ Bw,
    const float* __restrict__ bias,
    const float* __restrict__ qscale,
    unsigned short* __restrict__ oq,
    unsigned short* __restrict__ okv,
    unsigned short* __restrict__ ovt) {
  __shared__ __align__(16) unsigned short sA[64 * 64];
  __shared__ __align__(16) unsigned short sB[192 * 64];
  const int t = threadIdx.x, lane = t & 63, w = t >> 6;
  const int l15 = lane & 15, lg = lane >> 4;
  const int m0 = blockIdx.y * 64, n0 = blockIdx.x * 192;

  f32x4 acc[4][3] = {};

  for (int kb = 0; kb < 1024; kb += 64) {
    __syncthreads();
#pragma unroll
    for (int i = 0; i < 2; i++) {
      int idx = i * 256 + w * 64 + lane;
      int row = idx >> 3;
      int cg = (idx & 7) ^ (row & 7);
      GLDS(A + (size_t)(m0 + row) * 1024 + kb + cg * 8, sA + (i * 256 + w * 64) * 8);
    }
#pragma unroll
    for (int i = 0; i < 6; i++) {
      int idx = i * 256 + w * 64 + lane;
      int row = idx >> 3;
      int cg = (idx & 7) ^ (row & 7);
      GLDS(Bw + (size_t)(n0 + row) * 1024 + kb + cg * 8, sB + (i * 256 + w * 64) * 8);
    }
    __syncthreads();
    bf16x8 af[4][2], bfr[3][2];
#pragma unroll
    for (int rt = 0; rt < 4; rt++) {
      int row = rt * 16 + l15;
#pragma unroll
      for (int kk = 0; kk < 2; kk++) {
        int c = (kk * 4 + lg) ^ (row & 7);
        af[rt][kk] = *(const bf16x8*)((const char*)sA + row * 128 + c * 16);
      }
    }
#pragma unroll
    for (int ct = 0; ct < 3; ct++) {
      int rowb = w * 48 + ct * 16 + l15;
#pragma unroll
      for (int kk = 0; kk < 2; kk++) {
        int c = (kk * 4 + lg) ^ (rowb & 7);
        bfr[ct][kk] = *(const bf16x8*)((const char*)sB + rowb * 128 + c * 16);
      }
    }
#pragma unroll
    for (int kk = 0; kk < 2; kk++)
#pragma unroll
      for (int rt = 0; rt < 4; rt++)
#pragma unroll
        for (int ct = 0; ct < 3; ct++)
          acc[rt][ct] = mfma16(af[rt][kk], bfr[ct][kk], acc[rt][ct]);
  }

#pragma unroll
  for (int rt = 0; rt < 4; rt++) {
#pragma unroll
    for (int ct = 0; ct < 3; ct++) {
      int n = n0 + w * 48 + ct * 16 + l15;
      float bv = bias[n];
#pragma unroll
      for (int jj = 0; jj < 4; jj++) {
        int m = m0 + rt * 16 + lg * 4 + jj;
        float v = acc[rt][ct][jj] + bv;
        int b = m >> 11, s = m & 2047;
        if (n < 1024) {  // q: scaled, [b][h][s][d]
          int h = n >> 6, d = n & 63;
          v *= qscale[d];
          oq[(((size_t)(b * 16 + h) * 2048 + s) << 6) + d] = f2bf(v);
        } else if (n < 1280) {  // k: [b][kv][s][d]
          int kv = (n - 1024) >> 6, d = n & 63;
          okv[(((size_t)(b * 4 + kv) * 2048 + s) << 6) + d] = f2bf(v);
        } else {  // v transposed: [b][kv][d][s]
          int kv = (n - 1280) >> 6, d = n & 63;
          ovt[(((size_t)((b * 4 + kv) * 64 + d)) << 11) + s] = f2bf(v);
        }
      }
    }
  }
}

// ----------------------------------------------------- GEMM 2 (out proj) ----
// 64x128 tile -> grid (8,64) = 512 blocks = 2 blocks/CU. Transposed epilogue
// (r8): stage 32x64 f32 sub-tile in LDS (stride-68), store 4 full rows x
// 256B contiguous per instruction.
__global__ __launch_bounds__(256, 2) void gemm2_kernel(
    const unsigned short* __restrict__ A,    // [4096][1024] bf16
    const unsigned short* __restrict__ Bw,   // [1024][1024] bf16 (o_w)
    const float* __restrict__ bias,
    float* __restrict__ of) {
  __shared__ __align__(16) unsigned short sA[64 * 64];
  __shared__ __align__(16) unsigned short sB[128 * 64];
  __shared__ __align__(16) float sT[4][32 * 68];
  const int t = threadIdx.x, lane = t & 63, w = t >> 6;
  const int l15 = lane & 15, lg = lane >> 4;
  const int m0 = blockIdx.y * 64, n0 = blockIdx.x * 128;
  const int wr = w >> 1, wc = w & 1;  // 2x2 wave grid over 64x128

  f32x4 acc[2][4] = {};

  for (int kb = 0; kb < 1024; kb += 64) {
    __syncthreads();
#pragma unroll
    for (int i = 0; i < 2; i++) {
      int idx = i * 256 + w * 64 + lane;
      int row = idx >> 3;
      int cg = (idx & 7) ^ (row & 7);
      GLDS(A + (size_t)(m0 + row) * 1024 + kb + cg * 8, sA + (i * 256 + w * 64) * 8);
    }
#pragma unroll
    for (int i = 0; i < 4; i++) {
      int idx = i * 256 + w * 64 + lane;
      int row = idx >> 3;
      int cg = (idx & 7) ^ (row & 7);
      GLDS(Bw + (size_t)(n0 + row) * 1024 + kb + cg * 8, sB + (i * 256 + w * 64) * 8);
    }
    __syncthreads();
    bf16x8 af[2][2], bfr[4][2];
#pragma unroll
    for (int rt = 0; rt < 2; rt++) {
      int row = wr * 32 + rt * 16 + l15;
#pragma unroll
      for (int kk = 0; kk < 2; kk++) {
        int c = (kk * 4 + lg) ^ (row & 7);
        af[rt][kk] = *(const bf16x8*)((const char*)sA + row * 128 + c * 16);
      }
    }
#pragma unroll
    for (int ct = 0; ct < 4; ct++) {
      int rowb = wc * 64 + ct * 16 + l15;
#pragma unroll
      for (int kk = 0; kk < 2; kk++) {
        int c = (kk * 4 + lg) ^ (rowb & 7);
        bfr[ct][kk] = *(const bf16x8*)((const char*)sB + rowb * 128 + c * 16);
      }
    }
#pragma unroll
    for (int kk = 0; kk < 2; kk++)
#pragma unroll
      for (int rt = 0; rt < 2; rt++)
#pragma unroll
        for (int ct = 0; ct < 4; ct++)
          acc[rt][ct] = mfma16(af[rt][kk], bfr[ct][kk], acc[rt][ct]);
  }

  // stage to LDS (per-wave region; within-wave dep, no barrier needed)
#pragma unroll
  for (int rt = 0; rt < 2; rt++)
#pragma unroll
    for (int ct = 0; ct < 4; ct++)
#pragma unroll
      for (int jj = 0; jj < 4; jj++) {
        int r = rt * 16 + lg * 4 + jj;
        int cc = ct * 16 + l15;
        sT[w][r * 68 + cc] = acc[rt][ct][jj];
      }
  // read back row-major; each instr: 4 full rows x 256B contiguous stores
#pragma unroll
  for (int i = 0; i < 8; i++) {
    int r = i * 4 + lg;
    int cc = l15 * 4;
    f32x4 v = *(const f32x4*)&sT[w][r * 68 + cc];
    int n = n0 + wc * 64 + cc;
    float4 bv = *(const float4*)(bias + n);
    v[0] += bv.x; v[1] += bv.y; v[2] += bv.z; v[3] += bv.w;
    int m = m0 + wr * 32 + r;
    *(f32x4*)(of + (size_t)m * 1024 + n) = v;
  }
}

// -------------------------------------------------------------- attention ---
// Fused-pair: block = (bh, p) handles q-tiles A=p and B=31-p with ONE K-sweep
// per pass. Balanced p remap; rotation start = bid & 15 (r4). r7/r8:
// LDS-transposed score + zero-strip stores. r9: shared-ak dual-half QK.
// r10: vectorized rowsum accumulators. r11: normalization folded into the
// QK MFMA accumulator (p = exp2(s + lrinv), the add is free).
//
// THIS REVISION: PHASE-BALANCED ZERO STRIP. All 512 blocks run pass 1
// (zero stores) then pass 2 (all 537MB of stores) in device-wide near-
// lockstep (per-CU iteration sums are constant by the r3 balance) -> the
// store pipe idles in phase 1 and saturates in phase 2. Move the residual
// zero strip (~126MB; exactly p col-blocks per block, p <= 15 < NB) into
// pass 1, one 8-store chunk per iteration -> pass 2's store load drops to
// ~411MB, strip drains through pass 1's idle store pipe. (r1 tested this
// pre-r7 when stores were transaction-limited scatter - regime mismatch;
// post-r7 the stream is byte-limited, where phase balance pays.)
//
// Pass-1 vmcnt with strip chunks (chunk S_j issued at END of iter j for
// j < p): younger-than-G_j at iter j's wait = S_{j-2}(8 if j-2<p) +
// G_{j+1}(2 if staged) + S_{j-1}(8 if j-1<p) + G_{j+2}(2 if staged)
// -> WV(base + s0 + s1), base = 4/2/0 by staging; exact values enumerated
// {0,2,4,8,10,12,16,18,20}. Strips are never force-drained until the final
// WV(0) (>= 15 iters later).
//
// LDS (56KB pool, 2 blocks/CU):
//   [0,32K):  K buffers. pass1: 4 bufs (2-deep prefetch, 1 barrier/iter).
//             pass2: bufs 0-1; [16K,32K) = Sw (4 waves x 4KB f32 staging).
//   [32K,48K): VT 2 bufs (pass2 only).
//   [48K,56K): sP (4 waves x 2KB bf16 P).
//
// vmcnt pass2 (4 GLDS + 8 stores per iter): j==0 [G0(4),G1(4)] -> WV(4);
// steady [G_j(4),S_{j-1}(8),G_{j+1}(4)] -> WV(12); last -> WV(8).
__global__ __launch_bounds__(256, 2) void attn_kernel(
    const unsigned short* __restrict__ q_ws,
    const unsigned short* __restrict__ k_ws,
    const unsigned short* __restrict__ v_ws,
    float* __restrict__ scores,
    unsigned short* __restrict__ attn_bf) {
  __shared__ __align__(16) unsigned char smem[57344];

  const int t = threadIdx.x, lane = t & 63, w = t >> 6;
  const int l15 = lane & 15, lg = lane >> 4;
  int bid = blockIdx.x;
  int bh = bid & 31;            // b*16+h
  int pr = bid >> 5;            // 0..15
  int p = (bid < 256) ? pr : (23 - pr);  // balance: bid & bid+256 -> p & 15-p
  int b = bh >> 4, h = bh & 15, kv = h >> 2;
  const int qtA = p, qtB = 31 - p;
  const int NB = qtB + 1;       // 17..32 k-tiles (covers A's p+1)
  const int start = bid & 15;   // == bh & 15: panel-lockstep rotation (r4)

  const unsigned short* Kp = k_ws + ((size_t)(b * 4 + kv) * 2048) * 64;
  const unsigned short* Vp = v_ws + ((size_t)(b * 4 + kv) * 64) * 2048;  // [d][s]
  const int qrA = qtA * 64 + w * 16 + l15;   // this lane's A q-row
  const int qrB = qtB * 64 + w * 16 + l15;   // this lane's B q-row

  auto rot = [&](int j) { int n = j + start; return (n >= NB) ? n - NB : n; };
  auto kbuf = [&](int i) { return (unsigned short*)(smem + i * 8192); };
  auto vbuf = [&](int i) { return (unsigned short*)(smem + 32768 + i * 8192); };
  float* Sw = (float*)(smem + 16384 + w * 4096);       // pass2 f32 staging
  unsigned char* myP = smem + 49152 + w * 2048;

  float* SpA = scores + ((size_t)bh * 2048 + qtA * 64) * 2048;
  float* SpB = scores + ((size_t)bh * 2048 + qtB * 64) * 2048;

  // per-lane Q fragments (compiler-tracked; FORCE4 drains them before staging)
  bf16x8 aqA[2], aqB[2];
  {
    const unsigned short* qa = q_ws + ((size_t)bh * 2048 + qrA) * 64;
    const unsigned short* qb = q_ws + ((size_t)bh * 2048 + qrB) * 64;
    aqA[0] = *(const bf16x8*)(qa + lg * 8);
    aqA[1] = *(const bf16x8*)(qa + 32 + lg * 8);
    aqB[0] = *(const bf16x8*)(qb + lg * 8);
    aqB[1] = *(const bf16x8*)(qb + 32 + lg * 8);
    FORCE4(*(f32x4*)&aqA[0]); FORCE4(*(f32x4*)&aqA[1]);
    FORCE4(*(f32x4*)&aqB[0]); FORCE4(*(f32x4*)&aqB[1]);
  }

  auto stageK = [&](int kt, int bufi) {  // 2 GLDS per wave
#pragma unroll
    for (int i = 0; i < 2; i++) {
      int idx = i * 256 + w * 64 + lane;
      int row = idx >> 3;
      int cg = (idx & 7) ^ (row & 7);
      GLDS(Kp + (size_t)(kt * 64 + row) * 64 + cg * 8, kbuf(bufi) + (i * 256 + w * 64) * 8);
    }
  };
  auto stageVT = [&](int kt, int bufi) {  // 2 GLDS per wave
#pragma unroll
    for (int i = 0; i < 2; i++) {
      int idx = i * 256 + w * 64 + lane;
      int row = idx >> 3;
      int cg = (idx & 7) ^ (row & 7);
      GLDS(Vp + (size_t)row * 2048 + kt * 64 + cg * 8, vbuf(bufi) + (i * 256 + w * 64) * 8);
    }
  };
  // swapped QK^T: K rows as A, Q as B -> acc[ct][j] = S[q=l15][k0+ct*16+lg*4+j]
  auto qk_tile = [&](const unsigned short* kb, const bf16x8(&aq)[2], f32x4(&acc)[4]) {
#pragma unroll
    for (int ct = 0; ct < 4; ct++) {
      int row = ct * 16 + l15;
#pragma unroll
      for (int kk = 0; kk < 2; kk++) {
        int c = (kk * 4 + lg) ^ (row & 7);
        bf16x8 ak = *(const bf16x8*)((const char*)kb + row * 128 + c * 16);
        acc[ct] = mfma16(ak, aq[kk], acc[ct]);
      }
    }
  };
  // dual-half QK sharing the ak fragment read (both halves active)
  auto qk_tile2 = [&](const unsigned short* kb, f32x4(&accB)[4], f32x4(&accA)[4]) {
#pragma unroll
    for (int ct = 0; ct < 4; ct++) {
      int row = ct * 16 + l15;
#pragma unroll
      for (int kk = 0; kk < 2; kk++) {
        int c = (kk * 4 + lg) ^ (row & 7);
        bf16x8 ak = *(const bf16x8*)((const char*)kb + row * 128 + c * 16);
        accB[ct] = mfma16(ak, aqB[kk], accB[ct]);
        accA[ct] = mfma16(ak, aqA[kk], accA[ct]);
      }
    }
  };
  // LDS-transposed contiguous store of a 16x64 f32 tile.
  auto tstore = [&](float* Sp, const f32x4(&acc)[4], int k0) {
#pragma unroll
    for (int ct = 0; ct < 4; ct++) {
      int xs = (ct * 4 + lg) ^ l15;
      *(f32x4*)(Sw + l15 * 64 + xs * 4) = acc[ct];
    }
#pragma unroll
    for (int i = 0; i < 4; i++) {
      int r = i * 4 + lg;
      int xs = l15 ^ r;
      f32x4 v = *(const f32x4*)(Sw + r * 64 + xs * 4);
      *(f32x4*)(Sp + (size_t)(w * 16 + r) * 2048 + k0 + l15 * 4) = v;
    }
  };

  // ---- pass 1: rowsums + phase-balanced zero strip, 4-buf 2-deep ----
  stageK(rot(0), 0);
  stageK(rot(1), 1);
  f32x4 rsvA[4] = {}, rsvB[4] = {};
  for (int j = 0; j < NB; j++) {
    const int n = rot(j);
    int base;
    if (j + 2 < NB) { stageK(rot(j + 2), (j + 2) & 3); base = 4; }
    else if (j + 1 < NB) base = 2;
    else base = 0;
    // strip chunks S_{j-1}, S_{j-2} are younger than G_j in the queue
    int s0 = (j >= 1 && (j - 1) < p) ? 8 : 0;
    int s1 = (j >= 2 && (j - 2) < p) ? 8 : 0;
    switch (base + s0 + s1) {
      case 0:  WV(0);  break;
      case 2:  WV(2);  break;
      case 4:  WV(4);  break;
      case 8:  WV(8);  break;
      case 10: WV(10); break;
      case 12: WV(12); break;
      case 16: WV(16); break;
      case 18: WV(18); break;
      default: WV(20); break;
    }
    SBAR();
    const unsigned short* kb = kbuf(j & 3);
    const bool doA = (n <= qtA);
    f32x4 aB4[4] = {}, aA4[4] = {};
    if (doA) { qk_tile2(kb, aB4, aA4); } else { qk_tile(kb, aqB, aB4); }
    if (n < NB - 1) {
#pragma unroll
      for (int ct = 0; ct < 4; ct++)
#pragma unroll
        for (int jj = 0; jj < 4; jj++)
          rsvB[ct][jj] += __builtin_amdgcn_exp2f(aB4[ct][jj]);
    } else {
#pragma unroll
      for (int ct = 0; ct < 4; ct++) {
        int kb0 = n * 64 + ct * 16 + lg * 4;
#pragma unroll
        for (int jj = 0; jj < 4; jj++)
          rsvB[ct][jj] += (kb0 + jj <= qrB) ? __builtin_amdgcn_exp2f(aB4[ct][jj]) : 0.f;
      }
    }
    if (doA) {
      if (n < qtA) {
#pragma unroll
        for (int ct = 0; ct < 4; ct++)
#pragma unroll
          for (int jj = 0; jj < 4; jj++)
            rsvA[ct][jj] += __builtin_amdgcn_exp2f(aA4[ct][jj]);
      } else {
#pragma unroll
        for (int ct = 0; ct < 4; ct++) {
          int kb0 = n * 64 + ct * 16 + lg * 4;
#pragma unroll
          for (int jj = 0; jj < 4; jj++)
            rsvA[ct][jj] += (kb0 + jj <= qrA) ? __builtin_amdgcn_exp2f(aA4[ct][jj]) : 0.f;
        }
      }
    }
    // zero-strip chunk j (cols (NB+j)*64 .. +64 for all 64 rows, A and B):
    // fire-and-forget; drains through pass 1's otherwise-idle store pipe.
    if (j < p) {
      int c0 = (NB + j) * 64;
      f32x4 z = {0.f, 0.f, 0.f, 0.f};
#pragma unroll
      for (int i = 0; i < 4; i++) {
        int r = i * 4 + lg;
        *(f32x4*)(SpA + (size_t)(w * 16 + r) * 2048 + c0 + l15 * 4) = z;
        *(f32x4*)(SpB + (size_t)(w * 16 + r) * 2048 + c0 + l15 * 4) = z;
      }
    }
    // no bottom barrier: 4-buffer skew (n-1, n, n+2 distinct mod 4)
  }
  f32x4 sB4 = rsvB[0] + rsvB[1];
  sB4 += rsvB[2] + rsvB[3];
  float rsB = (sB4[0] + sB4[1]) + (sB4[2] + sB4[3]);
  f32x4 sA4 = rsvA[0] + rsvA[1];
  sA4 += rsvA[2] + rsvA[3];
  float rsA = (sA4[0] + sA4[1]) + (sA4[2] + sA4[3]);
  rsA += __shfl_xor(rsA, 16); rsA += __shfl_xor(rsA, 32);
  rsB += __shfl_xor(rsB, 16); rsB += __shfl_xor(rsB, 32);
  // fold normalization into exp2: p = exp2(s + lr), lr = -log2(rowsum)
  float lrA = -__log2f(rsA), lrB = -__log2f(rsB);

  SBAR();  // pass-1 readers done before pass-2 staging reuses buffers

  // ---- pass 2: transposed P stores + in-loop zeros + PV, 2-buf ----
  stageK(rot(0), 0); stageVT(rot(0), 0);
  f32x4 accoA[4] = {}, accoB[4] = {};
  const int xr = (l15 & 7) << 4;
  const f32x4 initB = {lrB, lrB, lrB, lrB};
  const f32x4 initA = {lrA, lrA, lrA, lrA};

  for (int j = 0; j < NB; j++) {
    const int n = rot(j);
    if (j + 1 < NB) { stageK(rot(j + 1), (j + 1) & 1); stageVT(rot(j + 1), (j + 1) & 1); }
    if (j == 0) { WV(4); }
    else if (j + 1 < NB) { WV(12); }
    else { WV(8); }
    SBAR();
    const unsigned short* kb = kbuf(j & 1);
    const unsigned short* vt = vbuf(j & 1);
    int k0 = n * 64;
    const bool doA = (n <= qtA);

    // QK with lrinv pre-loaded in the accumulator (the add is free)
    f32x4 aB4[4] = {initB, initB, initB, initB};
    f32x4 aA4[4] = {initA, initA, initA, initA};
    if (doA) { qk_tile2(kb, aB4, aA4); } else { qk_tile(kb, aqB, aB4); }

    // ---- B half: softmax (no muls), transposed store, pack, PV ----
    {
      if (n == NB - 1) {
#pragma unroll
        for (int ct = 0; ct < 4; ct++) {
          int kb0 = k0 + ct * 16 + lg * 4;
#pragma unroll
          for (int jj = 0; jj < 4; jj++)
            aB4[ct][jj] = (kb0 + jj <= qrB) ? __builtin_amdgcn_exp2f(aB4[ct][jj]) : 0.f;
        }
      } else {
#pragma unroll
        for (int ct = 0; ct < 4; ct++)
#pragma unroll
          for (int jj = 0; jj < 4; jj++)
            aB4[ct][jj] = __builtin_amdgcn_exp2f(aB4[ct][jj]);
      }
      tstore(SpB, aB4, k0);
#pragma unroll
      for (int ct = 0; ct < 4; ct++) {
        uint2 pw;
        pw.x = cvt_pk(aB4[ct][0], aB4[ct][1]);
        pw.y = cvt_pk(aB4[ct][2], aB4[ct][3]);
        *(uint2*)(myP + l15 * 128 + ((ct * 32 + lg * 8) ^ xr)) = pw;
      }
#pragma unroll
      for (int kk = 0; kk < 2; kk++) {
        bf16x8 ap = *(const bf16x8*)(myP + l15 * 128 + ((kk * 64 + lg * 16) ^ xr));
#pragma unroll
        for (int ct = 0; ct < 4; ct++) {
          int vrow = ct * 16 + l15;
          int cv = (kk * 4 + lg) ^ (vrow & 7);
          bf16x8 bv = *(const bf16x8*)((const char*)vt + vrow * 128 + cv * 16);
          accoB[ct] = mfma16(bv, ap, accoB[ct]);
        }
      }
    }

    // ---- A half (or transposed-pattern zero tile) ----
    if (doA) {
      if (n == qtA) {
#pragma unroll
        for (int ct = 0; ct < 4; ct++) {
          int kb0 = k0 + ct * 16 + lg * 4;
#pragma unroll
          for (int jj = 0; jj < 4; jj++)
            aA4[ct][jj] = (kb0 + jj <= qrA) ? __builtin_amdgcn_exp2f(aA4[ct][jj]) : 0.f;
        }
      } else {
#pragma unroll
        for (int ct = 0; ct < 4; ct++)
#pragma unroll
          for (int jj = 0; jj < 4; jj++)
            aA4[ct][jj] = __builtin_amdgcn_exp2f(aA4[ct][jj]);
      }
      tstore(SpA, aA4, k0);
#pragma unroll
      for (int ct = 0; ct < 4; ct++) {
        uint2 pw;
        pw.x = cvt_pk(aA4[ct][0], aA4[ct][1]);
        pw.y = cvt_pk(aA4[ct][2], aA4[ct][3]);
        *(uint2*)(myP + l15 * 128 + ((ct * 32 + lg * 8) ^ xr)) = pw;
      }
#pragma unroll
      for (int kk = 0; kk < 2; kk++) {
        bf16x8 ap = *(const bf16x8*)(myP + l15 * 128 + ((kk * 64 + lg * 16) ^ xr));
#pragma unroll
        for (int ct = 0; ct < 4; ct++) {
          int vrow = ct * 16 + l15;
          int cv = (kk * 4 + lg) ^ (vrow & 7);
          bf16x8 bv = *(const bf16x8*)((const char*)vt + vrow * 128 + cv * 16);
          accoA[ct] = mfma16(bv, ap, accoA[ct]);
        }
      }
    } else {
      f32x4 z = {0.f, 0.f, 0.f, 0.f};
#pragma unroll
      for (int i = 0; i < 4; i++) {
        int r = i * 4 + lg;
        *(f32x4*)(SpA + (size_t)(w * 16 + r) * 2048 + k0 + l15 * 4) = z;
      }
    }
    SBAR();  // protect 2-buf K/V for next iter's staging
  }

  // O stores: lane holds O[q=l15][d=ct*16+lg*4+..] -> packed uint2
  {
    int mA = b * 2048 + qtA * 64 + w * 16 + l15;
    int mB = b * 2048 + qtB * 64 + w * 16 + l15;
    unsigned int* oA = (unsigned int*)(attn_bf + (size_t)mA * 1024 + h * 64);
    unsigned int* oB = (unsigned int*)(attn_bf + (size_t)mB * 1024 + h * 64);
#pragma unroll
    for (int ct = 0; ct < 4; ct++) {
      uint2 pa, pb;
      pa.x = cvt_pk(accoA[ct][0], accoA[ct][1]);
      pa.y = cvt_pk(accoA[ct][2], accoA[ct][3]);
      pb.x = cvt_pk(accoB[ct][0], accoB[ct][1]);
      pb.y = cvt_pk(accoB[ct][2], accoB[ct][3]);
      *(uint2*)(oA + (ct * 16 + lg * 4) / 2) = pa;
      *(uint2*)(oB + (ct * 16 + lg * 4) / 2) = pb;
    }
  }
}

// ----------------------------------------------------------------- launch ---
extern "C" void kernel_launch(void* const* d_in, const int* in_sizes, int n_in,
                              void* d_out, int out_size, void* d_ws, size_t ws_size,
                              hipStream_t stream) {
  const float* hidden  = (const float*)d_in[0];
  // d_in[1] = mask: causal by construction; applied analytically.
  const float* scaling = (const float*)d_in[2];
  const float* qkv_w   = (const float*)d_in[3];
  const float* qkv_b   = (const float*)d_in[4];
  const float* o_w     = (const float*)d_in[5];
  const float* o_b     = (const float*)d_in[6];

  float* scores = (float*)d_out;                                 // [2][16][2048][2048]
  float* outp   = (float*)d_out + (size_t)2 * 16 * 2048 * 2048;  // [4096][1024]

  char* ws = (char*)d_ws;
  unsigned short* hidden_bf = (unsigned short*)(ws + 0);          //  8 MB
  unsigned short* qkvw_bf   = (unsigned short*)(ws + 8388608);    //  3 MB
  unsigned short* ow_bf     = (unsigned short*)(ws + 11534336);   //  2 MB
  unsigned short* q_ws      = (unsigned short*)(ws + 13631488);   //  8 MB
  unsigned short* k_ws      = (unsigned short*)(ws + 22020096);   //  2 MB
  unsigned short* v_ws      = (unsigned short*)(ws + 24117248);   //  2 MB
  unsigned short* attn_bf   = (unsigned short*)(ws + 26214400);   //  8 MB
  float* qscale             = (float*)(ws + 34603008);            //  256 B

  convert_kernel<<<512, 256, 0, stream>>>(hidden, qkv_w, o_w, scaling,
                                          hidden_bf, qkvw_bf, ow_bf, qscale);
  gemm_kernel<<<dim3(8, 64), 256, 0, stream>>>(hidden_bf, qkvw_bf, qkv_b,
                                               qscale, q_ws, k_ws, v_ws);
  attn_kernel<<<512, 256, 0, stream>>>(q_ws, k_ws, v_ws, scores, attn_bf);
  gemm2_kernel<<<dim3(8, 64), 256, 0, stream>>>(attn_bf, ow_bf, o_b, outp);
}